// Round 6
// baseline (739.275 us; speedup 1.0000x reference)
//
#include <hip/hip_runtime.h>
#include <math.h>

constexpr int NN = 40000;
constexpr int NE = 640000;
constexpr int KD = 129;     // contraction dim (time + 128 space)

constexpr float LOG2E = 1.4426950408889634f;
constexpr float SC_C  = 0.35355339059327373f * LOG2E;   // 2/sqrt(32) * log2(e)

// ---- transposed-weight buffer offsets (in floats) ----
constexpr int OFF_IN   = 0;
constexpr int OFF_QKV0 = OFF_IN   + KD*128;
constexpr int OFF_QKV1 = OFF_QKV0 + KD*384;
constexpr int OFF_OUT0 = OFF_QKV1 + KD*384;
constexpr int OFF_OUT1 = OFF_OUT0 + KD*128;
constexpr int OFF_OUTP = OFF_OUT1 + KD*128;
constexpr int WT_TOTAL = OFF_OUTP + KD*128;   // 165120 floats

struct QkvPtrs {
  float* sp0; float* tp0;
  float* sp1; float* tp1;
  float* sp2; float* tp2;
};

// =================== small utility kernels ===================

__global__ void zero_i32(int* p, int n) {
  int i = blockIdx.x * 256 + threadIdx.x;
  if (i < n) p[i] = 0;
}

// transpose all weights to k-major once per call
__global__ void prep_wt(const float* __restrict__ in_w, const float* __restrict__ q_w,
                        const float* __restrict__ k_w, const float* __restrict__ v_w,
                        const float* __restrict__ out_w, const float* __restrict__ outp_w,
                        float* __restrict__ WT) {
  int t = blockIdx.x * 256 + threadIdx.x;
  if (t >= KD * 1280) return;
  int k = t / 1280, c = t % 1280;
  float v; int dst;
  if (c < 128) {
    v = in_w[(size_t)c * KD + k];
    dst = OFF_IN + k * 128 + c;
  } else if (c < 896) {
    int l = (c - 128) / 384, cc = (c - 128) % 384;
    int arr = cc >> 7, r = cc & 127;
    const float* w = arr == 0 ? q_w : (arr == 1 ? k_w : v_w);
    v = w[((size_t)l * 128 + r) * KD + k];
    dst = (l == 0 ? OFF_QKV0 : OFF_QKV1) + k * 384 + cc;
  } else if (c < 1152) {
    int l = (c - 896) / 128, r = (c - 896) % 128;
    v = out_w[((size_t)l * 128 + r) * KD + k];
    dst = (l == 0 ? OFF_OUT0 : OFF_OUT1) + k * 128 + r;
  } else {
    int r = c - 1152;
    v = outp_w[(size_t)r * KD + k];
    dst = OFF_OUTP + k * 128 + r;
  }
  WT[dst] = v;
}

__global__ void prep_bias(const float* __restrict__ q_b, const float* __restrict__ k_b,
                          const float* __restrict__ v_b, float* __restrict__ bq) {
  int t = blockIdx.x * 256 + threadIdx.x;
  if (t >= 768) return;
  int l = t / 384, c = t % 384;
  int arr = c >> 7, r = c & 127;
  const float* b = arr == 0 ? q_b : (arr == 1 ? k_b : v_b);
  bq[t] = b[l * 128 + r];
}

// =================== CSR build ===================

__global__ void count_kernel(const int* __restrict__ dst, int* __restrict__ counts, int E) {
  int e = blockIdx.x * 256 + threadIdx.x;
  if (e < E) atomicAdd(&counts[dst[e]], 1);
}

__global__ void __launch_bounds__(1024) scan_kernel(const int* __restrict__ counts,
                                                    int* __restrict__ ro, int n) {
  __shared__ int wsum[16];
  __shared__ int carry;
  int tid = threadIdx.x, wid = tid >> 6, lane = tid & 63;
  if (tid == 0) { carry = 0; ro[0] = 0; }
  __syncthreads();
  for (int base = 0; base < n; base += 1024) {
    int idx = base + tid;
    int v = (idx < n) ? counts[idx] : 0;
    int s = v;
    #pragma unroll
    for (int off = 1; off < 64; off <<= 1) {
      int t = __shfl_up(s, off);
      if (lane >= off) s += t;
    }
    if (lane == 63) wsum[wid] = s;
    __syncthreads();
    if (wid == 0) {
      int ws = (lane < 16) ? wsum[lane] : 0;
      #pragma unroll
      for (int off = 1; off < 16; off <<= 1) {
        int t = __shfl_up(ws, off);
        if (lane >= off) ws += t;
      }
      if (lane < 16) wsum[lane] = ws;
    }
    __syncthreads();
    int woff = (wid > 0) ? wsum[wid - 1] : 0;
    if (idx < n) ro[idx + 1] = s + woff + carry;
    int total = wsum[15];
    __syncthreads();
    if (tid == 0) carry += total;
    __syncthreads();
  }
}

// also emits inv_e: CSR position of each original edge id
__global__ void scatter_kernel(const int* __restrict__ src, const int* __restrict__ dst,
                               const int* __restrict__ ro, int* __restrict__ cursor,
                               int* __restrict__ s_csr, int* __restrict__ inv_e, int E) {
  int e = blockIdx.x * 256 + threadIdx.x;
  if (e >= E) return;
  int d = dst[e];
  int pos = ro[d] + atomicAdd(&cursor[d], 1);
  s_csr[pos] = src[e];
  inv_e[e] = pos;
}

// =================== edge-bias precompute (both layers, CSR-ordered out) ===================
// eb_w layout: [2][4][16] = 128 floats. Output is pre-scaled into log2-domain:
//   eb_out = SC_C + (ef @ ebw.T) * LOG2E   (so score = fma(dp_total, SC_C, eb_out))
__global__ __launch_bounds__(256) void ebias_kernel(const float* __restrict__ ef,
                                                    const float* __restrict__ ebw,
                                                    const int* __restrict__ inv_e,
                                                    float* __restrict__ eb) {
  __shared__ float w[128];
  if (threadIdx.x < 128) w[threadIdx.x] = ebw[threadIdx.x];
  __syncthreads();
  int e = blockIdx.x * 256 + threadIdx.x;
  if (e >= NE) return;
  float f[16];
  #pragma unroll
  for (int i = 0; i < 4; i++) *(float4*)&f[i * 4] = *(const float4*)(ef + (size_t)e * 16 + i * 4);
  int pos = inv_e[e];
  #pragma unroll
  for (int l = 0; l < 2; l++) {
    float4 o;
    float* op = &o.x;
    #pragma unroll
    for (int h = 0; h < 4; h++) {
      float acc = 0.f;
      #pragma unroll
      for (int i = 0; i < 16; i++) acc = fmaf(f[i], w[l * 64 + h * 16 + i], acc);
      op[h] = fmaf(acc, LOG2E, SC_C);
    }
    *(float4*)(eb + (size_t)l * NE * 4 + (size_t)pos * 4) = o;
  }
}

// =================== expmap0 ===================
// block = 256 = 4 nodes x 64 lanes; writes split state (hs, ht)
__global__ void expmap_kernel(const float* __restrict__ x, float* __restrict__ hs,
                              float* __restrict__ ht) {
  int nl = threadIdx.x >> 6, lane = threadIdx.x & 63;
  int n = blockIdx.x * 4 + nl;
  if (n >= NN) return;
  const float* xr = x + (size_t)n * 128;
  float v0 = xr[lane], v1 = xr[lane + 64];
  float ss = v0 * v0 + v1 * v1;
  #pragma unroll
  for (int off = 1; off < 64; off <<= 1) ss += __shfl_xor(ss, off);
  float nn = sqrtf(fmaxf(ss, 1e-12f));
  float s = sinhf(nn) / nn;
  float* hr = hs + (size_t)n * 128;
  if (lane == 0) ht[n] = coshf(nn);
  hr[lane] = s * v0;
  hr[lane + 64] = s * v1;
}

// =================== register-resident node GEMM ===================
// block = 64 nodes x 128 cols, 256 threads; thread = 1 node x 32 cols.
// Wave = 64 nodes x one 32-col group -> W address is wave-uniform (scalar loads).
// A rows stream through per-lane float4 loads. No LDS in the K-loop.
// EPI: 0 = LN+ReLU+lift, 1 = per-head lift (qkv), 2 = midpoint2+LN+lift, 3 = logmap0
template<int EPI>
__global__ __launch_bounds__(256, 4) void node_gemm(
    const float* __restrict__ As, const float* __restrict__ At,
    const float* __restrict__ WT, int outc,
    const float* __restrict__ bias,
    float* __restrict__ outS, float* __restrict__ outT, QkvPtrs qo,
    const float* __restrict__ resS, const float* __restrict__ resT,
    const float* __restrict__ gv, const float* __restrict__ bvv) {
  __shared__ float red[2][64][5];
  const int tid = threadIdx.x;
  const int ln = tid & 63;                                    // node within block
  const int grp = __builtin_amdgcn_readfirstlane(tid >> 6);   // col group (wave-uniform)
  const int n = blockIdx.x * 64 + ln;
  const int cb = blockIdx.y;
  const int colOff = (cb << 7) + (grp << 5);

  float acc[32];
  { // k = 0 (time row) folded into init together with bias
    float at = At[n];
    const float* w0 = WT + colOff;
    #pragma unroll
    for (int i = 0; i < 8; i++) {
      float4 b4 = *(const float4*)(bias + colOff + i * 4);
      float4 w4 = *(const float4*)(w0 + i * 4);
      acc[i * 4 + 0] = fmaf(at, w4.x, b4.x);
      acc[i * 4 + 1] = fmaf(at, w4.y, b4.y);
      acc[i * 4 + 2] = fmaf(at, w4.z, b4.z);
      acc[i * 4 + 3] = fmaf(at, w4.w, b4.w);
    }
  }
  const float* Arow = As + (size_t)n * 128;
  for (int k4 = 0; k4 < 32; k4++) {
    float a4[4];
    *(float4*)a4 = *(const float4*)(Arow + (k4 << 2));
    #pragma unroll
    for (int kk = 0; kk < 4; kk++) {
      const float* wp = WT + (size_t)(1 + (k4 << 2) + kk) * outc + colOff;
      float av = a4[kk];
      #pragma unroll
      for (int i = 0; i < 8; i++) {
        float4 w4 = *(const float4*)(wp + i * 4);
        acc[i * 4 + 0] = fmaf(av, w4.x, acc[i * 4 + 0]);
        acc[i * 4 + 1] = fmaf(av, w4.y, acc[i * 4 + 1]);
        acc[i * 4 + 2] = fmaf(av, w4.z, acc[i * 4 + 2]);
        acc[i * 4 + 3] = fmaf(av, w4.w, acc[i * 4 + 3]);
      }
    }
  }

  const int c0 = grp << 5;   // col base within the 128-col output block

  if constexpr (EPI == 0) {           // LayerNorm + ReLU + lift
    float s = 0.f, s2 = 0.f;
    #pragma unroll
    for (int j = 0; j < 32; j++) { s += acc[j]; s2 += acc[j] * acc[j]; }
    red[0][ln][grp] = s; red[1][ln][grp] = s2;
    __syncthreads();
    float S = 0.f, S2 = 0.f;
    #pragma unroll
    for (int q = 0; q < 4; q++) { S += red[0][ln][q]; S2 += red[1][ln][q]; }
    float mu = S * (1.f / 128.f);
    float var = S2 * (1.f / 128.f) - mu * mu;
    float rstd = 1.f / sqrtf(var + 1e-5f);
    float ss = 0.f;
    #pragma unroll
    for (int j = 0; j < 32; j++) {
      float z = (acc[j] - mu) * rstd * gv[c0 + j] + bvv[c0 + j];
      z = fmaxf(z, 0.f);
      ss += z * z;
      acc[j] = z;
    }
    __syncthreads();
    red[0][ln][grp] = ss;
    __syncthreads();
    float SS = red[0][ln][0] + red[0][ln][1] + red[0][ln][2] + red[0][ln][3];
    float* orow = outS + (size_t)n * 128 + c0;
    #pragma unroll
    for (int i = 0; i < 8; i++) *(float4*)(orow + i * 4) = *(float4*)&acc[i * 4];
    if (grp == 0) outT[n] = sqrtf(1.f + SS);
  } else if constexpr (EPI == 1) {    // per-head lift: thread's 32 cols = one head
    float* sp = cb == 0 ? qo.sp0 : (cb == 1 ? qo.sp1 : qo.sp2);
    float* tp = cb == 0 ? qo.tp0 : (cb == 1 ? qo.tp1 : qo.tp2);
    const int tst = (cb == 0) ? 1 : 2;   // k/v time coords interleave into ktv float2
    float ss = 0.f;
    #pragma unroll
    for (int j = 0; j < 32; j++) ss += acc[j] * acc[j];
    tp[((size_t)n * 4 + grp) * tst] = sqrtf(1.f + ss);
    float* srow = sp + (size_t)n * 128 + c0;
    #pragma unroll
    for (int i = 0; i < 8; i++) *(float4*)(srow + i * 4) = *(float4*)&acc[i * 4];
  } else if constexpr (EPI == 2) {    // lift + midpoint2(res) + LayerNorm + lift
    float sy = 0.f;
    #pragma unroll
    for (int j = 0; j < 32; j++) sy += acc[j] * acc[j];
    red[0][ln][grp] = sy;
    __syncthreads();
    float SY = red[0][ln][0] + red[0][ln][1] + red[0][ln][2] + red[0][ln][3];
    float t_att = sqrtf(1.f + SY);
    float a0 = 0.5f * (t_att + resT[n]);
    const float* rrow = resS + (size_t)n * 128 + c0;
    float sa = 0.f, su = 0.f;
    #pragma unroll
    for (int i = 0; i < 8; i++) {
      float4 r4 = *(const float4*)(rrow + i * 4);
      const float* rp = &r4.x;
      #pragma unroll
      for (int q = 0; q < 4; q++) {
        float a = 0.5f * (acc[i * 4 + q] + rp[q]);
        acc[i * 4 + q] = a;
        sa += a * a;
        su += a;
      }
    }
    __syncthreads();
    red[0][ln][grp] = sa; red[1][ln][grp] = su;
    __syncthreads();
    float SA = 0.f, SU = 0.f;
    #pragma unroll
    for (int q = 0; q < 4; q++) { SA += red[0][ln][q]; SU += red[1][ln][q]; }
    float den = sqrtf(fmaxf(fabsf(a0 * a0 - SA), 1e-8f));
    float inv = 1.f / den;
    float mu = SU * inv * (1.f / 128.f);
    float var = SA * inv * inv * (1.f / 128.f) - mu * mu;
    float rstd = 1.f / sqrtf(var + 1e-5f);
    float ss = 0.f;
    #pragma unroll
    for (int j = 0; j < 32; j++) {
      float z = (acc[j] * inv - mu) * rstd * gv[c0 + j] + bvv[c0 + j];
      ss += z * z;
      acc[j] = z;
    }
    __syncthreads();
    red[0][ln][grp] = ss;
    __syncthreads();
    float SS = red[0][ln][0] + red[0][ln][1] + red[0][ln][2] + red[0][ln][3];
    float* orow = outS + (size_t)n * 128 + c0;
    #pragma unroll
    for (int i = 0; i < 8; i++) *(float4*)(orow + i * 4) = *(float4*)&acc[i * 4];
    if (grp == 0) outT[n] = sqrtf(1.f + SS);
  } else {                            // EPI == 3: lift + logmap0 (packed out)
    float s = 0.f;
    #pragma unroll
    for (int j = 0; j < 32; j++) s += acc[j] * acc[j];
    red[0][ln][grp] = s;
    __syncthreads();
    float S = red[0][ln][0] + red[0][ln][1] + red[0][ln][2] + red[0][ln][3];
    float nn = sqrtf(fmaxf(S, 1e-12f));
    float t0 = sqrtf(1.f + S);
    float al = fmaxf(t0, 1.f + 1e-7f);
    float sc = acoshf(al) / nn;
    float* orow = outS + (size_t)n * 128 + c0;
    #pragma unroll
    for (int j = 0; j < 32; j++) acc[j] *= sc;
    #pragma unroll
    for (int i = 0; i < 8; i++) *(float4*)(orow + i * 4) = *(float4*)&acc[i * 4];
  }
}

// =================== fused edge attention (score + online softmax + aggregate) ===================
// 4 nodes per 256-thread block; one wave per node; lane = (head h = lane/16, d2 = lane%16)
// Processes 4 edges per online-softmax step (one rescale per 4 edges, batched gathers).

#define LOADB(P, JB)                                                        \
  do {                                                                      \
    _Pragma("unroll")                                                       \
    for (int i = 0; i < 4; i++) {                                           \
      int pos = r0 + (JB) + i;                                              \
      int vld = pos < r1;                                                   \
      int cp = vld ? pos : (r1 - 1);                                        \
      int s = s_csr[cp];                                                    \
      int so = s * 128 + hb + d2;                                           \
      P##k0[i] = ks[so];      P##k1[i] = ks[so + 16];                       \
      P##v0[i] = vs[so];      P##v1[i] = vs[so + 16];                       \
      float2 tv = ktv[(size_t)s * 4 + h];                                   \
      P##kt[i] = tv.x;        P##vt[i] = tv.y;                              \
      P##eb[i] = vld ? ebias[(size_t)cp * 4 + h] : -1e30f;                  \
    }                                                                       \
  } while (0)

#define COMPB(P)                                                            \
  do {                                                                      \
    float dpa = fmaf(q1, P##k1[0], q0 * P##k0[0]);                          \
    float dpb = fmaf(q1, P##k1[1], q0 * P##k0[1]);                          \
    float dpc = fmaf(q1, P##k1[2], q0 * P##k0[2]);                          \
    float dpd = fmaf(q1, P##k1[3], q0 * P##k0[3]);                          \
    dpa += __shfl_xor(dpa, 1); dpb += __shfl_xor(dpb, 1);                   \
    dpc += __shfl_xor(dpc, 1); dpd += __shfl_xor(dpd, 1);                   \
    dpa += __shfl_xor(dpa, 2); dpb += __shfl_xor(dpb, 2);                   \
    dpc += __shfl_xor(dpc, 2); dpd += __shfl_xor(dpd, 2);                   \
    dpa += __shfl_xor(dpa, 4); dpb += __shfl_xor(dpb, 4);                   \
    dpc += __shfl_xor(dpc, 4); dpd += __shfl_xor(dpd, 4);                   \
    dpa += __shfl_xor(dpa, 8); dpb += __shfl_xor(dpb, 8);                   \
    dpc += __shfl_xor(dpc, 8); dpd += __shfl_xor(dpd, 8);                   \
    float sca = fmaf(fmaf(-qth, P##kt[0], dpa), SC_C, P##eb[0]);            \
    float scb = fmaf(fmaf(-qth, P##kt[1], dpb), SC_C, P##eb[1]);            \
    float scc = fmaf(fmaf(-qth, P##kt[2], dpc), SC_C, P##eb[2]);            \
    float scd = fmaf(fmaf(-qth, P##kt[3], dpd), SC_C, P##eb[3]);            \
    float mN = fmaxf(fmaxf(fmaxf(sca, scb), fmaxf(scc, scd)), m);           \
    float scale = __builtin_amdgcn_exp2f(m - mN);                           \
    float wa = __builtin_amdgcn_exp2f(sca - mN);                            \
    float wb = __builtin_amdgcn_exp2f(scb - mN);                            \
    float wc = __builtin_amdgcn_exp2f(scc - mN);                            \
    float wd = __builtin_amdgcn_exp2f(scd - mN);                            \
    den  = fmaf(den,  scale, (wa + wb) + (wc + wd));                        \
    acc0 = fmaf(acc0, scale,                                                \
        fmaf(wa, P##v0[0], fmaf(wb, P##v0[1], fmaf(wc, P##v0[2], wd * P##v0[3])))); \
    acc1 = fmaf(acc1, scale,                                                \
        fmaf(wa, P##v1[0], fmaf(wb, P##v1[1], fmaf(wc, P##v1[2], wd * P##v1[3])))); \
    acct = fmaf(acct, scale,                                                \
        fmaf(wa, P##vt[0], fmaf(wb, P##vt[1], fmaf(wc, P##vt[2], wd * P##vt[3])))); \
    m = mN;                                                                 \
  } while (0)

__global__ __launch_bounds__(256) void edge_attn_kernel(const int* __restrict__ ro,
                                                        const int* __restrict__ s_csr,
                                                        const float* __restrict__ ebias,
                                                        const float* __restrict__ qs,
                                                        const float* __restrict__ qt,
                                                        const float* __restrict__ ks,
                                                        const float2* __restrict__ ktv,
                                                        const float* __restrict__ vs,
                                                        float* __restrict__ aggS,
                                                        float* __restrict__ aggT) {
  int n = blockIdx.x * 4 + (threadIdx.x >> 6);
  if (n >= NN) return;
  int lane = threadIdx.x & 63;
  int h = lane >> 4, d2 = lane & 15;
  const int hb = h << 5;
  int r0 = ro[n], r1 = ro[n + 1];
  int deg = r1 - r0;

  int qoff = n * 128 + hb + d2;
  float q0 = qs[qoff], q1 = qs[qoff + 16];
  float qth = qt[(size_t)n * 4 + h];

  float m = -1e30f, den = 0.f, acc0 = 0.f, acc1 = 0.f, acct = 0.f;

  if (deg > 0) {
    float Ak0[4], Ak1[4], Av0[4], Av1[4], Akt[4], Avt[4], Aeb[4];
    float Bk0[4], Bk1[4], Bv0[4], Bv1[4], Bkt[4], Bvt[4], Beb[4];
    LOADB(A, 0);
    int jb = 0;
    while (true) {
      if (jb + 4 < deg) LOADB(B, jb + 4);
      COMPB(A);
      jb += 4;
      if (jb >= deg) break;
      if (jb + 4 < deg) LOADB(A, jb + 4);
      COMPB(B);
      jb += 4;
      if (jb >= deg) break;
    }
  }

  float inv = 1.f / (den + 1e-16f);
  float a0 = acc0 * inv, a1 = acc1 * inv;
  float at = acct * inv;
  float p = a0 * a0 + a1 * a1;
  p += __shfl_xor(p, 1);
  p += __shfl_xor(p, 2);
  p += __shfl_xor(p, 4);
  p += __shfl_xor(p, 8);
  float dh = sqrtf(fmaxf(fabsf(at * at - p), 1e-8f));
  float o0 = a0 / dh, o1 = a1 / dh;
  float q = o0 * o0 + o1 * o1;
  q += __shfl_xor(q, 1);
  q += __shfl_xor(q, 2);
  q += __shfl_xor(q, 4);
  q += __shfl_xor(q, 8);
  q += __shfl_xor(q, 16);
  q += __shfl_xor(q, 32);
  float* ar = aggS + (size_t)n * 128;
  if (lane == 0) aggT[n] = sqrtf(1.f + q);
  ar[hb + d2] = o0;
  ar[hb + 16 + d2] = o1;
}

// =================== launch ===================

extern "C" void kernel_launch(void* const* d_in, const int* in_sizes, int n_in,
                              void* d_out, int out_size, void* d_ws, size_t ws_size,
                              hipStream_t stream) {
  const float* x      = (const float*)d_in[0];
  const int*   ei     = (const int*)  d_in[1];
  const float* ef     = (const float*)d_in[2];
  const float* in_w   = (const float*)d_in[3];
  const float* in_b   = (const float*)d_in[4];
  const float* in_g   = (const float*)d_in[5];
  const float* in_bb  = (const float*)d_in[6];
  const float* q_w    = (const float*)d_in[7];
  const float* q_b    = (const float*)d_in[8];
  const float* k_w    = (const float*)d_in[9];
  const float* k_b    = (const float*)d_in[10];
  const float* v_w    = (const float*)d_in[11];
  const float* v_b    = (const float*)d_in[12];
  const float* out_w  = (const float*)d_in[13];
  const float* out_b  = (const float*)d_in[14];
  const float* eb_w   = (const float*)d_in[15];
  const float* norm_g = (const float*)d_in[16];
  const float* norm_b = (const float*)d_in[17];
  const float* outp_w = (const float*)d_in[18];
  const float* outp_b = (const float*)d_in[19];

  const int* srcI = ei;
  const int* dstI = ei + NE;

  // ---- carve workspace ----
  char* base = (char*)d_ws;
  size_t off = 0;
  auto carve = [&](size_t bytes) -> char* {
    char* p = base + off;
    off = (off + bytes + 255) & ~(size_t)255;
    return p;
  };
  float* hs0    = (float*)carve((size_t)NN * 128 * 4);
  float* ht0    = (float*)carve((size_t)NN * 4);
  float* hs1    = (float*)carve((size_t)NN * 128 * 4);
  float* ht1    = (float*)carve((size_t)NN * 4);
  float* qs     = (float*)carve((size_t)NN * 128 * 4);
  float* qt     = (float*)carve((size_t)NN * 4 * 4);
  float* ks     = (float*)carve((size_t)NN * 128 * 4);
  float* vs     = (float*)carve((size_t)NN * 128 * 4);
  float2* ktv   = (float2*)carve((size_t)NN * 4 * 8);
  float* ebias  = (float*)carve((size_t)2 * NE * 4 * 4);
  int*   s_csr  = (int*)  carve((size_t)NE * 4);
  int*   inv_e  = (int*)  carve((size_t)NE * 4);
  int*   ro     = (int*)  carve((size_t)(NN + 1) * 4);
  int*   counts = (int*)  carve((size_t)NN * 4);
  float* WT     = (float*)carve((size_t)WT_TOTAL * 4);
  float* bq     = (float*)carve((size_t)768 * 4);
  if (off > ws_size) return;  // workspace too small; bail

  QkvPtrs qkvp{qs, qt, ks, (float*)ktv, vs, (float*)ktv + 1};
  QkvPtrs qz{nullptr, nullptr, nullptr, nullptr, nullptr, nullptr};

  // ---- weight prep ----
  prep_wt<<<(KD * 1280 + 255) / 256, 256, 0, stream>>>(in_w, q_w, k_w, v_w, out_w, outp_w, WT);
  prep_bias<<<3, 256, 0, stream>>>(q_b, k_b, v_b, bq);

  // ---- CSR build (by dst) ----
  zero_i32<<<(NN + 255) / 256, 256, 0, stream>>>(counts, NN);
  count_kernel<<<NE / 256, 256, 0, stream>>>(dstI, counts, NE);
  scan_kernel<<<1, 1024, 0, stream>>>(counts, ro, NN);
  zero_i32<<<(NN + 255) / 256, 256, 0, stream>>>(counts, NN);
  scatter_kernel<<<NE / 256, 256, 0, stream>>>(srcI, dstI, ro, counts, s_csr, inv_e, NE);

  // ---- edge biases for both layers (CSR-ordered, log2-domain) ----
  ebias_kernel<<<(NE + 255) / 256, 256, 0, stream>>>(ef, eb_w, inv_e, ebias);

  // ---- input embedding ----
  expmap_kernel<<<NN / 4, 256, 0, stream>>>(x, hs0, ht0);
  node_gemm<0><<<dim3(NN / 64, 1), 256, 0, stream>>>(hs0, ht0, WT + OFF_IN, 128, in_b,
                                                     hs0, ht0, qz, nullptr, nullptr,
                                                     in_g, in_bb);

  // ---- layers ----
  float* hcS = hs0; float* hcT = ht0;
  float* hoS = hs1; float* hoT = ht1;
  for (int l = 0; l < 2; l++) {
    node_gemm<1><<<dim3(NN / 64, 3), 256, 0, stream>>>(
        hcS, hcT, WT + (l ? OFF_QKV1 : OFF_QKV0), 384, bq + l * 384,
        nullptr, nullptr, qkvp, nullptr, nullptr, nullptr, nullptr);
    edge_attn_kernel<<<NN / 4, 256, 0, stream>>>(ro, s_csr, ebias + (size_t)l * NE * 4,
                                                 qs, qt, ks, ktv, vs, hoS, hoT);
    node_gemm<2><<<dim3(NN / 64, 1), 256, 0, stream>>>(
        hoS, hoT, WT + (l ? OFF_OUT1 : OFF_OUT0), 128, out_b + l * 128,
        hoS, hoT, qz, hcS, hcT, norm_g + l * 128, norm_b + l * 128);
    float* t;
    t = hcS; hcS = hoS; hoS = t;
    t = hcT; hcT = hoT; hoT = t;
  }

  // ---- output projection + logmap ----
  node_gemm<3><<<dim3(NN / 64, 1), 256, 0, stream>>>(hcS, hcT, WT + OFF_OUTP, 128, outp_b,
                                                     (float*)d_out, nullptr, qz,
                                                     nullptr, nullptr, nullptr, nullptr);
}

// Round 7
// 668.308 us; speedup vs baseline: 1.1062x; 1.1062x over previous
//
#include <hip/hip_runtime.h>
#include <math.h>

constexpr int NN = 40000;
constexpr int NE = 640000;
constexpr int KD = 129;     // contraction dim (time + 128 space)

constexpr float LOG2E = 1.4426950408889634f;
constexpr float SC_C  = 0.35355339059327373f * LOG2E;   // 2/sqrt(32) * log2(e)

// ---- transposed-weight buffer offsets (in floats) ----
constexpr int OFF_IN   = 0;
constexpr int OFF_QKV0 = OFF_IN   + KD*128;
constexpr int OFF_QKV1 = OFF_QKV0 + KD*384;
constexpr int OFF_OUT0 = OFF_QKV1 + KD*384;
constexpr int OFF_OUT1 = OFF_OUT0 + KD*128;
constexpr int OFF_OUTP = OFF_OUT1 + KD*128;
constexpr int WT_TOTAL = OFF_OUTP + KD*128;   // 165120 floats

struct QkvPtrs {
  float* sp0; float* tp0;
  float* sp1; float* tp1;
  float* sp2; float* tp2;
};

// =================== small utility kernels ===================

__global__ void zero_i32(int* p, int n) {
  int i = blockIdx.x * 256 + threadIdx.x;
  if (i < n) p[i] = 0;
}

// transpose all weights to k-major once per call
__global__ void prep_wt(const float* __restrict__ in_w, const float* __restrict__ q_w,
                        const float* __restrict__ k_w, const float* __restrict__ v_w,
                        const float* __restrict__ out_w, const float* __restrict__ outp_w,
                        float* __restrict__ WT) {
  int t = blockIdx.x * 256 + threadIdx.x;
  if (t >= KD * 1280) return;
  int k = t / 1280, c = t % 1280;
  float v; int dst;
  if (c < 128) {
    v = in_w[(size_t)c * KD + k];
    dst = OFF_IN + k * 128 + c;
  } else if (c < 896) {
    int l = (c - 128) / 384, cc = (c - 128) % 384;
    int arr = cc >> 7, r = cc & 127;
    const float* w = arr == 0 ? q_w : (arr == 1 ? k_w : v_w);
    v = w[((size_t)l * 128 + r) * KD + k];
    dst = (l == 0 ? OFF_QKV0 : OFF_QKV1) + k * 384 + cc;
  } else if (c < 1152) {
    int l = (c - 896) / 128, r = (c - 896) % 128;
    v = out_w[((size_t)l * 128 + r) * KD + k];
    dst = (l == 0 ? OFF_OUT0 : OFF_OUT1) + k * 128 + r;
  } else {
    int r = c - 1152;
    v = outp_w[(size_t)r * KD + k];
    dst = OFF_OUTP + k * 128 + r;
  }
  WT[dst] = v;
}

__global__ void prep_bias(const float* __restrict__ q_b, const float* __restrict__ k_b,
                          const float* __restrict__ v_b, float* __restrict__ bq) {
  int t = blockIdx.x * 256 + threadIdx.x;
  if (t >= 768) return;
  int l = t / 384, c = t % 384;
  int arr = c >> 7, r = c & 127;
  const float* b = arr == 0 ? q_b : (arr == 1 ? k_b : v_b);
  bq[t] = b[l * 128 + r];
}

// =================== CSR build ===================

__global__ void count_kernel(const int* __restrict__ dst, int* __restrict__ counts, int E) {
  int e = blockIdx.x * 256 + threadIdx.x;
  if (e < E) atomicAdd(&counts[dst[e]], 1);
}

__global__ void __launch_bounds__(1024) scan_kernel(const int* __restrict__ counts,
                                                    int* __restrict__ ro, int n) {
  __shared__ int wsum[16];
  __shared__ int carry;
  int tid = threadIdx.x, wid = tid >> 6, lane = tid & 63;
  if (tid == 0) { carry = 0; ro[0] = 0; }
  __syncthreads();
  for (int base = 0; base < n; base += 1024) {
    int idx = base + tid;
    int v = (idx < n) ? counts[idx] : 0;
    int s = v;
    #pragma unroll
    for (int off = 1; off < 64; off <<= 1) {
      int t = __shfl_up(s, off);
      if (lane >= off) s += t;
    }
    if (lane == 63) wsum[wid] = s;
    __syncthreads();
    if (wid == 0) {
      int ws = (lane < 16) ? wsum[lane] : 0;
      #pragma unroll
      for (int off = 1; off < 16; off <<= 1) {
        int t = __shfl_up(ws, off);
        if (lane >= off) ws += t;
      }
      if (lane < 16) wsum[lane] = ws;
    }
    __syncthreads();
    int woff = (wid > 0) ? wsum[wid - 1] : 0;
    if (idx < n) ro[idx + 1] = s + woff + carry;
    int total = wsum[15];
    __syncthreads();
    if (tid == 0) carry += total;
    __syncthreads();
  }
}

// also emits inv_e: CSR position of each original edge id
__global__ void scatter_kernel(const int* __restrict__ src, const int* __restrict__ dst,
                               const int* __restrict__ ro, int* __restrict__ cursor,
                               int* __restrict__ s_csr, int* __restrict__ inv_e, int E) {
  int e = blockIdx.x * 256 + threadIdx.x;
  if (e >= E) return;
  int d = dst[e];
  int pos = ro[d] + atomicAdd(&cursor[d], 1);
  s_csr[pos] = src[e];
  inv_e[e] = pos;
}

// =================== edge-bias precompute (both layers, CSR-ordered out) ===================
// eb_w layout: [2][4][16] = 128 floats. Output is pre-scaled into log2-domain:
//   eb_out = SC_C + (ef @ ebw.T) * LOG2E   (so score = fma(dp_total, SC_C, eb_out))
__global__ __launch_bounds__(256) void ebias_kernel(const float* __restrict__ ef,
                                                    const float* __restrict__ ebw,
                                                    const int* __restrict__ inv_e,
                                                    float* __restrict__ eb) {
  __shared__ float w[128];
  if (threadIdx.x < 128) w[threadIdx.x] = ebw[threadIdx.x];
  __syncthreads();
  int e = blockIdx.x * 256 + threadIdx.x;
  if (e >= NE) return;
  float f[16];
  #pragma unroll
  for (int i = 0; i < 4; i++) *(float4*)&f[i * 4] = *(const float4*)(ef + (size_t)e * 16 + i * 4);
  int pos = inv_e[e];
  #pragma unroll
  for (int l = 0; l < 2; l++) {
    float4 o;
    float* op = &o.x;
    #pragma unroll
    for (int h = 0; h < 4; h++) {
      float acc = 0.f;
      #pragma unroll
      for (int i = 0; i < 16; i++) acc = fmaf(f[i], w[l * 64 + h * 16 + i], acc);
      op[h] = fmaf(acc, LOG2E, SC_C);
    }
    *(float4*)(eb + (size_t)l * NE * 4 + (size_t)pos * 4) = o;
  }
}

// =================== expmap0 ===================
// block = 256 = 4 nodes x 64 lanes; writes split state (hs, ht)
__global__ void expmap_kernel(const float* __restrict__ x, float* __restrict__ hs,
                              float* __restrict__ ht) {
  int nl = threadIdx.x >> 6, lane = threadIdx.x & 63;
  int n = blockIdx.x * 4 + nl;
  if (n >= NN) return;
  const float* xr = x + (size_t)n * 128;
  float v0 = xr[lane], v1 = xr[lane + 64];
  float ss = v0 * v0 + v1 * v1;
  #pragma unroll
  for (int off = 1; off < 64; off <<= 1) ss += __shfl_xor(ss, off);
  float nn = sqrtf(fmaxf(ss, 1e-12f));
  float s = sinhf(nn) / nn;
  float* hr = hs + (size_t)n * 128;
  if (lane == 0) ht[n] = coshf(nn);
  hr[lane] = s * v0;
  hr[lane + 64] = s * v1;
}

// =================== register-resident node GEMM ===================
// block = 64 nodes x 128 cols, 256 threads; thread = 1 node x 32 cols.
// Wave = 64 nodes x one 32-col group -> W address is wave-uniform (scalar loads).
// A rows stream through per-lane float4 loads. No LDS in the K-loop.
// EPI: 0 = LN+ReLU+lift, 1 = per-head lift (qkv), 2 = midpoint2+LN+lift, 3 = logmap0
template<int EPI>
__global__ __launch_bounds__(256, 4) void node_gemm(
    const float* __restrict__ As, const float* __restrict__ At,
    const float* __restrict__ WT, int outc,
    const float* __restrict__ bias,
    float* __restrict__ outS, float* __restrict__ outT, QkvPtrs qo,
    const float* __restrict__ resS, const float* __restrict__ resT,
    const float* __restrict__ gv, const float* __restrict__ bvv) {
  __shared__ float red[2][64][5];
  const int tid = threadIdx.x;
  const int ln = tid & 63;                                    // node within block
  const int grp = __builtin_amdgcn_readfirstlane(tid >> 6);   // col group (wave-uniform)
  const int n = blockIdx.x * 64 + ln;
  const int cb = blockIdx.y;
  const int colOff = (cb << 7) + (grp << 5);

  float acc[32];
  { // k = 0 (time row) folded into init together with bias
    float at = At[n];
    const float* w0 = WT + colOff;
    #pragma unroll
    for (int i = 0; i < 8; i++) {
      float4 b4 = *(const float4*)(bias + colOff + i * 4);
      float4 w4 = *(const float4*)(w0 + i * 4);
      acc[i * 4 + 0] = fmaf(at, w4.x, b4.x);
      acc[i * 4 + 1] = fmaf(at, w4.y, b4.y);
      acc[i * 4 + 2] = fmaf(at, w4.z, b4.z);
      acc[i * 4 + 3] = fmaf(at, w4.w, b4.w);
    }
  }
  const float* Arow = As + (size_t)n * 128;
  for (int k4 = 0; k4 < 32; k4++) {
    float a4[4];
    *(float4*)a4 = *(const float4*)(Arow + (k4 << 2));
    #pragma unroll
    for (int kk = 0; kk < 4; kk++) {
      const float* wp = WT + (size_t)(1 + (k4 << 2) + kk) * outc + colOff;
      float av = a4[kk];
      #pragma unroll
      for (int i = 0; i < 8; i++) {
        float4 w4 = *(const float4*)(wp + i * 4);
        acc[i * 4 + 0] = fmaf(av, w4.x, acc[i * 4 + 0]);
        acc[i * 4 + 1] = fmaf(av, w4.y, acc[i * 4 + 1]);
        acc[i * 4 + 2] = fmaf(av, w4.z, acc[i * 4 + 2]);
        acc[i * 4 + 3] = fmaf(av, w4.w, acc[i * 4 + 3]);
      }
    }
  }

  const int c0 = grp << 5;   // col base within the 128-col output block

  if constexpr (EPI == 0) {           // LayerNorm + ReLU + lift
    float s = 0.f, s2 = 0.f;
    #pragma unroll
    for (int j = 0; j < 32; j++) { s += acc[j]; s2 += acc[j] * acc[j]; }
    red[0][ln][grp] = s; red[1][ln][grp] = s2;
    __syncthreads();
    float S = 0.f, S2 = 0.f;
    #pragma unroll
    for (int q = 0; q < 4; q++) { S += red[0][ln][q]; S2 += red[1][ln][q]; }
    float mu = S * (1.f / 128.f);
    float var = S2 * (1.f / 128.f) - mu * mu;
    float rstd = 1.f / sqrtf(var + 1e-5f);
    float ss = 0.f;
    #pragma unroll
    for (int j = 0; j < 32; j++) {
      float z = (acc[j] - mu) * rstd * gv[c0 + j] + bvv[c0 + j];
      z = fmaxf(z, 0.f);
      ss += z * z;
      acc[j] = z;
    }
    __syncthreads();
    red[0][ln][grp] = ss;
    __syncthreads();
    float SS = red[0][ln][0] + red[0][ln][1] + red[0][ln][2] + red[0][ln][3];
    float* orow = outS + (size_t)n * 128 + c0;
    #pragma unroll
    for (int i = 0; i < 8; i++) *(float4*)(orow + i * 4) = *(float4*)&acc[i * 4];
    if (grp == 0) outT[n] = sqrtf(1.f + SS);
  } else if constexpr (EPI == 1) {    // per-head lift: thread's 32 cols = one head
    float* sp = cb == 0 ? qo.sp0 : (cb == 1 ? qo.sp1 : qo.sp2);
    float* tp = cb == 0 ? qo.tp0 : (cb == 1 ? qo.tp1 : qo.tp2);
    const int tst = (cb == 0) ? 1 : 2;   // k/v time coords interleave into ktv float2
    float ss = 0.f;
    #pragma unroll
    for (int j = 0; j < 32; j++) ss += acc[j] * acc[j];
    tp[((size_t)n * 4 + grp) * tst] = sqrtf(1.f + ss);
    float* srow = sp + (size_t)n * 128 + c0;
    #pragma unroll
    for (int i = 0; i < 8; i++) *(float4*)(srow + i * 4) = *(float4*)&acc[i * 4];
  } else if constexpr (EPI == 2) {    // lift + midpoint2(res) + LayerNorm + lift
    float sy = 0.f;
    #pragma unroll
    for (int j = 0; j < 32; j++) sy += acc[j] * acc[j];
    red[0][ln][grp] = sy;
    __syncthreads();
    float SY = red[0][ln][0] + red[0][ln][1] + red[0][ln][2] + red[0][ln][3];
    float t_att = sqrtf(1.f + SY);
    float a0 = 0.5f * (t_att + resT[n]);
    const float* rrow = resS + (size_t)n * 128 + c0;
    float sa = 0.f, su = 0.f;
    #pragma unroll
    for (int i = 0; i < 8; i++) {
      float4 r4 = *(const float4*)(rrow + i * 4);
      const float* rp = &r4.x;
      #pragma unroll
      for (int q = 0; q < 4; q++) {
        float a = 0.5f * (acc[i * 4 + q] + rp[q]);
        acc[i * 4 + q] = a;
        sa += a * a;
        su += a;
      }
    }
    __syncthreads();
    red[0][ln][grp] = sa; red[1][ln][grp] = su;
    __syncthreads();
    float SA = 0.f, SU = 0.f;
    #pragma unroll
    for (int q = 0; q < 4; q++) { SA += red[0][ln][q]; SU += red[1][ln][q]; }
    float den = sqrtf(fmaxf(fabsf(a0 * a0 - SA), 1e-8f));
    float inv = 1.f / den;
    float mu = SU * inv * (1.f / 128.f);
    float var = SA * inv * inv * (1.f / 128.f) - mu * mu;
    float rstd = 1.f / sqrtf(var + 1e-5f);
    float ss = 0.f;
    #pragma unroll
    for (int j = 0; j < 32; j++) {
      float z = (acc[j] * inv - mu) * rstd * gv[c0 + j] + bvv[c0 + j];
      ss += z * z;
      acc[j] = z;
    }
    __syncthreads();
    red[0][ln][grp] = ss;
    __syncthreads();
    float SS = red[0][ln][0] + red[0][ln][1] + red[0][ln][2] + red[0][ln][3];
    float* orow = outS + (size_t)n * 128 + c0;
    #pragma unroll
    for (int i = 0; i < 8; i++) *(float4*)(orow + i * 4) = *(float4*)&acc[i * 4];
    if (grp == 0) outT[n] = sqrtf(1.f + SS);
  } else {                            // EPI == 3: lift + logmap0 (packed out)
    float s = 0.f;
    #pragma unroll
    for (int j = 0; j < 32; j++) s += acc[j] * acc[j];
    red[0][ln][grp] = s;
    __syncthreads();
    float S = red[0][ln][0] + red[0][ln][1] + red[0][ln][2] + red[0][ln][3];
    float nn = sqrtf(fmaxf(S, 1e-12f));
    float t0 = sqrtf(1.f + S);
    float al = fmaxf(t0, 1.f + 1e-7f);
    float sc = acoshf(al) / nn;
    float* orow = outS + (size_t)n * 128 + c0;
    #pragma unroll
    for (int j = 0; j < 32; j++) acc[j] *= sc;
    #pragma unroll
    for (int i = 0; i < 8; i++) *(float4*)(orow + i * 4) = *(float4*)&acc[i * 4];
  }
}

// =================== fused edge attention (score + online softmax + aggregate) ===================
// 4 nodes per 256-thread block; one wave per node; lane = (head h = lane/16, d2 = lane%16)
// 4 edges per online-softmax step; s-indices prefetched one full batch ahead so every
// gather is issued with resident indices (breaks the s_csr->gather dependent chain).

#define LOADI(SI, JB)                                                       \
  do {                                                                      \
    _Pragma("unroll")                                                       \
    for (int i = 0; i < 4; i++) {                                           \
      int pos = r0 + (JB) + i;                                              \
      SI[i] = s_csr[pos < r1 ? pos : (r1 - 1)];                             \
    }                                                                       \
  } while (0)

#define LOADG(P, SI, JB)                                                    \
  do {                                                                      \
    _Pragma("unroll")                                                       \
    for (int i = 0; i < 4; i++) {                                           \
      int pos = r0 + (JB) + i;                                              \
      int vld = pos < r1;                                                   \
      int cp = vld ? pos : (r1 - 1);                                        \
      int so = SI[i] * 128 + hb + d2;                                       \
      P##k0[i] = ks[so];      P##k1[i] = ks[so + 16];                       \
      P##v0[i] = vs[so];      P##v1[i] = vs[so + 16];                       \
      float2 tv = ktv[(size_t)SI[i] * 4 + h];                               \
      P##kt[i] = tv.x;        P##vt[i] = tv.y;                              \
      P##eb[i] = vld ? ebias[(size_t)cp * 4 + h] : -1e30f;                  \
    }                                                                       \
  } while (0)

#define COMPB(P)                                                            \
  do {                                                                      \
    float dpa = fmaf(q1, P##k1[0], q0 * P##k0[0]);                          \
    float dpb = fmaf(q1, P##k1[1], q0 * P##k0[1]);                          \
    float dpc = fmaf(q1, P##k1[2], q0 * P##k0[2]);                          \
    float dpd = fmaf(q1, P##k1[3], q0 * P##k0[3]);                          \
    dpa += __shfl_xor(dpa, 1); dpb += __shfl_xor(dpb, 1);                   \
    dpc += __shfl_xor(dpc, 1); dpd += __shfl_xor(dpd, 1);                   \
    dpa += __shfl_xor(dpa, 2); dpb += __shfl_xor(dpb, 2);                   \
    dpc += __shfl_xor(dpc, 2); dpd += __shfl_xor(dpd, 2);                   \
    dpa += __shfl_xor(dpa, 4); dpb += __shfl_xor(dpb, 4);                   \
    dpc += __shfl_xor(dpc, 4); dpd += __shfl_xor(dpd, 4);                   \
    dpa += __shfl_xor(dpa, 8); dpb += __shfl_xor(dpb, 8);                   \
    dpc += __shfl_xor(dpc, 8); dpd += __shfl_xor(dpd, 8);                   \
    float sca = fmaf(fmaf(-qth, P##kt[0], dpa), SC_C, P##eb[0]);            \
    float scb = fmaf(fmaf(-qth, P##kt[1], dpb), SC_C, P##eb[1]);            \
    float scc = fmaf(fmaf(-qth, P##kt[2], dpc), SC_C, P##eb[2]);            \
    float scd = fmaf(fmaf(-qth, P##kt[3], dpd), SC_C, P##eb[3]);            \
    float mN = fmaxf(fmaxf(fmaxf(sca, scb), fmaxf(scc, scd)), m);           \
    float scale = __builtin_amdgcn_exp2f(m - mN);                           \
    float wa = __builtin_amdgcn_exp2f(sca - mN);                            \
    float wb = __builtin_amdgcn_exp2f(scb - mN);                            \
    float wc = __builtin_amdgcn_exp2f(scc - mN);                            \
    float wd = __builtin_amdgcn_exp2f(scd - mN);                            \
    den  = fmaf(den,  scale, (wa + wb) + (wc + wd));                        \
    acc0 = fmaf(acc0, scale,                                                \
        fmaf(wa, P##v0[0], fmaf(wb, P##v0[1], fmaf(wc, P##v0[2], wd * P##v0[3])))); \
    acc1 = fmaf(acc1, scale,                                                \
        fmaf(wa, P##v1[0], fmaf(wb, P##v1[1], fmaf(wc, P##v1[2], wd * P##v1[3])))); \
    acct = fmaf(acct, scale,                                                \
        fmaf(wa, P##vt[0], fmaf(wb, P##vt[1], fmaf(wc, P##vt[2], wd * P##vt[3])))); \
    m = mN;                                                                 \
  } while (0)

__global__ __launch_bounds__(256) void edge_attn_kernel(const int* __restrict__ ro,
                                                        const int* __restrict__ s_csr,
                                                        const float* __restrict__ ebias,
                                                        const float* __restrict__ qs,
                                                        const float* __restrict__ qt,
                                                        const float* __restrict__ ks,
                                                        const float2* __restrict__ ktv,
                                                        const float* __restrict__ vs,
                                                        float* __restrict__ aggS,
                                                        float* __restrict__ aggT) {
  int n = blockIdx.x * 4 + (threadIdx.x >> 6);
  if (n >= NN) return;
  int lane = threadIdx.x & 63;
  int h = lane >> 4, d2 = lane & 15;
  const int hb = h << 5;
  int r0 = ro[n], r1 = ro[n + 1];
  int deg = r1 - r0;

  int qoff = n * 128 + hb + d2;
  float q0 = qs[qoff], q1 = qs[qoff + 16];
  float qth = qt[(size_t)n * 4 + h];

  float m = -1e30f, den = 0.f, acc0 = 0.f, acc1 = 0.f, acct = 0.f;

  if (deg > 0) {
    float Ak0[4], Ak1[4], Av0[4], Av1[4], Akt[4], Avt[4], Aeb[4];
    float Bk0[4], Bk1[4], Bv0[4], Bv1[4], Bkt[4], Bvt[4], Beb[4];
    int sA[4], sB[4];
    LOADI(sA, 0);
    LOADG(A, sA, 0);
    LOADI(sB, 4);
    int jb = 0;
    while (true) {
      if (jb + 4 < deg) LOADG(B, sB, jb + 4);
      if (jb + 8 < deg) LOADI(sA, jb + 8);
      COMPB(A);
      jb += 4;
      if (jb >= deg) break;
      if (jb + 4 < deg) LOADG(A, sA, jb + 4);
      if (jb + 8 < deg) LOADI(sB, jb + 8);
      COMPB(B);
      jb += 4;
      if (jb >= deg) break;
    }
  }

  float inv = 1.f / (den + 1e-16f);
  float a0 = acc0 * inv, a1 = acc1 * inv;
  float at = acct * inv;
  float p = a0 * a0 + a1 * a1;
  p += __shfl_xor(p, 1);
  p += __shfl_xor(p, 2);
  p += __shfl_xor(p, 4);
  p += __shfl_xor(p, 8);
  float dh = sqrtf(fmaxf(fabsf(at * at - p), 1e-8f));
  float o0 = a0 / dh, o1 = a1 / dh;
  float q = o0 * o0 + o1 * o1;
  q += __shfl_xor(q, 1);
  q += __shfl_xor(q, 2);
  q += __shfl_xor(q, 4);
  q += __shfl_xor(q, 8);
  q += __shfl_xor(q, 16);
  q += __shfl_xor(q, 32);
  float* ar = aggS + (size_t)n * 128;
  if (lane == 0) aggT[n] = sqrtf(1.f + q);
  ar[hb + d2] = o0;
  ar[hb + 16 + d2] = o1;
}

// =================== launch ===================

extern "C" void kernel_launch(void* const* d_in, const int* in_sizes, int n_in,
                              void* d_out, int out_size, void* d_ws, size_t ws_size,
                              hipStream_t stream) {
  const float* x      = (const float*)d_in[0];
  const int*   ei     = (const int*)  d_in[1];
  const float* ef     = (const float*)d_in[2];
  const float* in_w   = (const float*)d_in[3];
  const float* in_b   = (const float*)d_in[4];
  const float* in_g   = (const float*)d_in[5];
  const float* in_bb  = (const float*)d_in[6];
  const float* q_w    = (const float*)d_in[7];
  const float* q_b    = (const float*)d_in[8];
  const float* k_w    = (const float*)d_in[9];
  const float* k_b    = (const float*)d_in[10];
  const float* v_w    = (const float*)d_in[11];
  const float* v_b    = (const float*)d_in[12];
  const float* out_w  = (const float*)d_in[13];
  const float* out_b  = (const float*)d_in[14];
  const float* eb_w   = (const float*)d_in[15];
  const float* norm_g = (const float*)d_in[16];
  const float* norm_b = (const float*)d_in[17];
  const float* outp_w = (const float*)d_in[18];
  const float* outp_b = (const float*)d_in[19];

  const int* srcI = ei;
  const int* dstI = ei + NE;

  // ---- carve workspace ----
  char* base = (char*)d_ws;
  size_t off = 0;
  auto carve = [&](size_t bytes) -> char* {
    char* p = base + off;
    off = (off + bytes + 255) & ~(size_t)255;
    return p;
  };
  float* hs0    = (float*)carve((size_t)NN * 128 * 4);
  float* ht0    = (float*)carve((size_t)NN * 4);
  float* hs1    = (float*)carve((size_t)NN * 128 * 4);
  float* ht1    = (float*)carve((size_t)NN * 4);
  float* qs     = (float*)carve((size_t)NN * 128 * 4);
  float* qt     = (float*)carve((size_t)NN * 4 * 4);
  float* ks     = (float*)carve((size_t)NN * 128 * 4);
  float* vs     = (float*)carve((size_t)NN * 128 * 4);
  float2* ktv   = (float2*)carve((size_t)NN * 4 * 8);
  float* ebias  = (float*)carve((size_t)2 * NE * 4 * 4);
  int*   s_csr  = (int*)  carve((size_t)NE * 4);
  int*   inv_e  = (int*)  carve((size_t)NE * 4);
  int*   ro     = (int*)  carve((size_t)(NN + 1) * 4);
  int*   counts = (int*)  carve((size_t)NN * 4);
  float* WT     = (float*)carve((size_t)WT_TOTAL * 4);
  float* bq     = (float*)carve((size_t)768 * 4);
  if (off > ws_size) return;  // workspace too small; bail

  QkvPtrs qkvp{qs, qt, ks, (float*)ktv, vs, (float*)ktv + 1};
  QkvPtrs qz{nullptr, nullptr, nullptr, nullptr, nullptr, nullptr};

  // ---- weight prep ----
  prep_wt<<<(KD * 1280 + 255) / 256, 256, 0, stream>>>(in_w, q_w, k_w, v_w, out_w, outp_w, WT);
  prep_bias<<<3, 256, 0, stream>>>(q_b, k_b, v_b, bq);

  // ---- CSR build (by dst) ----
  zero_i32<<<(NN + 255) / 256, 256, 0, stream>>>(counts, NN);
  count_kernel<<<NE / 256, 256, 0, stream>>>(dstI, counts, NE);
  scan_kernel<<<1, 1024, 0, stream>>>(counts, ro, NN);
  zero_i32<<<(NN + 255) / 256, 256, 0, stream>>>(counts, NN);
  scatter_kernel<<<NE / 256, 256, 0, stream>>>(srcI, dstI, ro, counts, s_csr, inv_e, NE);

  // ---- edge biases for both layers (CSR-ordered, log2-domain) ----
  ebias_kernel<<<(NE + 255) / 256, 256, 0, stream>>>(ef, eb_w, inv_e, ebias);

  // ---- input embedding ----
  expmap_kernel<<<NN / 4, 256, 0, stream>>>(x, hs0, ht0);
  node_gemm<0><<<dim3(NN / 64, 1), 256, 0, stream>>>(hs0, ht0, WT + OFF_IN, 128, in_b,
                                                     hs0, ht0, qz, nullptr, nullptr,
                                                     in_g, in_bb);

  // ---- layers ----
  float* hcS = hs0; float* hcT = ht0;
  float* hoS = hs1; float* hoT = ht1;
  for (int l = 0; l < 2; l++) {
    node_gemm<1><<<dim3(NN / 64, 3), 256, 0, stream>>>(
        hcS, hcT, WT + (l ? OFF_QKV1 : OFF_QKV0), 384, bq + l * 384,
        nullptr, nullptr, qkvp, nullptr, nullptr, nullptr, nullptr);
    edge_attn_kernel<<<NN / 4, 256, 0, stream>>>(ro, s_csr, ebias + (size_t)l * NE * 4,
                                                 qs, qt, ks, ktv, vs, hoS, hoT);
    node_gemm<2><<<dim3(NN / 64, 1), 256, 0, stream>>>(
        hoS, hoT, WT + (l ? OFF_OUT1 : OFF_OUT0), 128, out_b + l * 128,
        hoS, hoT, qz, hcS, hcT, norm_g + l * 128, norm_b + l * 128);
    float* t;
    t = hcS; hcS = hoS; hoS = t;
    t = hcT; hcT = hoT; hoT = t;
  }

  // ---- output projection + logmap ----
  node_gemm<3><<<dim3(NN / 64, 1), 256, 0, stream>>>(hcS, hcT, WT + OFF_OUTP, 128, outp_b,
                                                     (float*)d_out, nullptr, qz,
                                                     nullptr, nullptr, nullptr, nullptr);
}